// Round 6
// baseline (158.208 us; speedup 1.0000x reference)
//
#include <hip/hip_runtime.h>
#include <hip/hip_bf16.h>
#include <math.h>

#define HW2 262144              // 512*512
#define TWO_PI     6.28318530717958647693f
#define INV_TWO_PI 0.15915494309189533577f
#define LOG2E      1.44269504088896340736f

typedef float  f32x4  __attribute__((ext_vector_type(4)));
typedef float  f32x8  __attribute__((ext_vector_type(8)));
typedef short  s16x8  __attribute__((ext_vector_type(8)));
typedef short  s16x4  __attribute__((ext_vector_type(4)));
typedef unsigned short ushort_t;

template <int I> struct ic { static constexpr int v = I; };
template <int I, int N, typename F>
__device__ __forceinline__ void sfor(F&& f) {
    if constexpr (I < N) { f(ic<I>{}); sfor<I + 1, N>(f); }
}

__device__ __forceinline__ ushort_t bf16_hi(float v) {
    __hip_bfloat16 h = __float2bfloat16(v);
    return __builtin_bit_cast(ushort_t, h);
}
__device__ __forceinline__ float bf16_tof(ushort_t u) {
    unsigned int x = ((unsigned int)u) << 16;
    return __builtin_bit_cast(float, x);
}

// ---- ws layout (bytes) ----
// pcq    f32[5][64][12] @ 0      expanded gabor constants (15360 B)
//   per channel: [a,b,c,d, e,f,w0r,w1r, br,0,0,0]
//   t = a*x0^2 + b*x0x1 + c*x1^2 + d*x0 + e*x1 + f   (exp2 domain)
// whi    u16[4][64][64] @ 15360  lin_w hi-bf16, row-major [c_out][k]
// wlo    u16[4][64][64] @ 48128  lin_w lo-bf16
// wouthi u16[16][64]    @ 80896  out_w hi (rows 3..15 zero)
// woutlo u16[16][64]    @ 82944
#define WS_WHI  15360
#define WS_WLO  48128
#define WS_WOH  80896
#define WS_WOL  82944

__global__ void gabor_pre(const float* __restrict__ filt_w,
                          const float* __restrict__ filt_b,
                          const float* __restrict__ mu,
                          const float* __restrict__ gamma,
                          const float* __restrict__ theta,
                          const float* __restrict__ lin_w,
                          const float* __restrict__ out_w,
                          float* __restrict__ pcq,
                          ushort_t* __restrict__ whi, ushort_t* __restrict__ wlo,
                          ushort_t* __restrict__ wouthi, ushort_t* __restrict__ woutlo) {
    int t = blockIdx.x * 256 + threadIdx.x;
    if (t < 320) {
        int i = t;
        float ang = TWO_PI * theta[i];
        float cs = cosf(ang), sn = sinf(ang);
        float g0 = gamma[i*2+0], g1 = gamma[i*2+1];
        float g0s = g0*g0, g1s = g1*g1;
        float cs2 = cs*cs, sn2 = sn*sn;
        float A = -0.5f * LOG2E * (g0s*cs2 + g1s*sn2);
        float B = -LOG2E * (cs*sn*(g0s - g1s));
        float C = -0.5f * LOG2E * (g0s*sn2 + g1s*cs2);
        float m0 = mu[i*2+0], m1 = mu[i*2+1];
        float* o = pcq + i*12;
        o[0] = A;  o[1] = B;  o[2] = C;
        o[3] = -(2.0f*A*m0 + B*m1);
        o[4] = -(B*m0 + 2.0f*C*m1);
        o[5] = A*m0*m0 + B*m0*m1 + C*m1*m1;
        o[6] = filt_w[i*2+0] * INV_TWO_PI;
        o[7] = filt_w[i*2+1] * INV_TWO_PI;
        o[8] = filt_b[i] * INV_TWO_PI;
        o[9] = 0.0f; o[10] = 0.0f; o[11] = 0.0f;
    } else if (t < 320 + 16384) {
        int i = t - 320;                       // l*4096 + c*64 + k
        float w = lin_w[i];
        ushort_t h = bf16_hi(w);
        whi[i] = h;
        wlo[i] = bf16_hi(w - bf16_tof(h));
    } else if (t < 320 + 16384 + 1024) {
        int i = t - (320 + 16384);             // m*64 + k
        int m = i >> 6;
        float w = (m < 3) ? out_w[i] : 0.0f;   // pad rows 3..15 with zeros
        ushort_t h = bf16_hi(w);
        wouthi[i] = h;
        woutlo[i] = bf16_hi(w - bf16_tof(h));
    }
}

// expanded gabor eval: x02,x11,x12 shared per pixel (computed once)
__device__ __forceinline__ float geval(f32x4 qa, f32x4 qb, float br,
                                       float x0, float x1,
                                       float x02, float x11, float x12) {
    float t = fmaf(qa[0], x02, fmaf(qa[1], x11,
              fmaf(qa[2], x12, fmaf(qa[3], x0, fmaf(qb[0], x1, qb[1])))));
    float e  = __builtin_amdgcn_exp2f(t);
    float sa = fmaf(qb[2], x0, fmaf(qb[3], x1, br));
    return e * __builtin_amdgcn_sinf(sa);
}

// One wave = 64 pixels; 2 waves/block (separate 16KB LDS halves) to lift the
// workgroup-slot occupancy cap seen in R5 (21% at 1-wave blocks).
// GEMM per layer: D[c,px] = W[c,k] h[k,px], mfma_f32_16x16x32_bf16,
// 3-product split-bf16 (ah*bh + ah*bl + al*bh; al*bl ~ 2^-18, dropped).
//   A frag: m = lane&15, k = (lane>>4)*8 + j
//   B frag: n = lane&15, k = (lane>>4)*8 + j
//   C/D:    col n = lane&15, row m = (lane>>4)*4 + reg
// h LDS per wave: hi plane @0, lo plane @8192, [px][c] bf16 rows of 128B,
// 16B-block XOR swizzle: block' = block ^ (px&7).
__global__ __launch_bounds__(128, 2) void gabor_mfma(
    const float* __restrict__ x, const float* __restrict__ lin_b,
    const float* __restrict__ out_b, const float* __restrict__ pcq,
    const ushort_t* __restrict__ whi, const ushort_t* __restrict__ wlo,
    const ushort_t* __restrict__ wouthi, const ushort_t* __restrict__ woutlo,
    float* __restrict__ out) {
    __shared__ __attribute__((aligned(16))) unsigned char hbuf2[2][16384];
    const int lane = threadIdx.x & 63;
    const int wid  = threadIdx.x >> 6;
    const int g    = lane >> 4;
    const int lm   = lane & 15;
    const int base = blockIdx.x * 128 + wid * 64;
    unsigned char* hbuf = hbuf2[wid];

    f32x4 x0v, x1v, x02v, x11v, x12v;
    int pixo[4];
    sfor<0, 4>([&](auto NI) {
        int P  = base + NI.v*16 + lm;
        int bb = P >> 18, pix = P & (HW2 - 1);
        const float* xb = x + bb*(2*HW2) + pix;
        float a = xb[0], b = xb[HW2];
        x0v[NI.v] = a;  x1v[NI.v] = b;
        x02v[NI.v] = a*a;  x11v[NI.v] = a*b;  x12v[NI.v] = b*b;
        pixo[NI.v] = bb*(3*HW2) + pix;
    });

    // ---- layer 0: h0 = gabor, computed directly at B-frag positions ----
    sfor<0, 2>([&](auto KC) {
        f32x8 vv[4];
        sfor<0, 8>([&](auto J) {
            const float* q = pcq + (KC.v*32 + g*8 + J.v)*12;
            f32x4 qa = *(const f32x4*)q, qb = *(const f32x4*)(q + 4);
            float br = q[8];
            sfor<0, 4>([&](auto NI) {
                vv[NI.v][J.v] = geval(qa, qb, br, x0v[NI.v], x1v[NI.v],
                                      x02v[NI.v], x11v[NI.v], x12v[NI.v]);
            });
        });
        sfor<0, 4>([&](auto NI) {
            s16x8 fh, fl;
            sfor<0, 8>([&](auto J) {
                float v = vv[NI.v][J.v];
                ushort_t h = bf16_hi(v);
                fh[J.v] = (short)h;
                fl[J.v] = (short)bf16_hi(v - bf16_tof(h));
            });
            int px  = NI.v*16 + lm;
            int blk = (4*KC.v + g) ^ (px & 7);
            char* p0 = (char*)hbuf + px*128 + blk*16;
            *(s16x8*)(p0)        = fh;
            *(s16x8*)(p0 + 8192) = fl;
        });
    });

    // ---- layers 1..4: nh = gabor * (W h + b) ----
#pragma unroll 1
    for (int l = 1; l <= 4; ++l) {
        __syncthreads();
        const ushort_t* whl = whi + (l-1)*4096;
        const ushort_t* wll = wlo + (l-1)*4096;
        const float*    bv  = lin_b + (l-1)*64;
        f32x4 acc[4][4];
        sfor<0, 4>([&](auto MI) {
            f32x4 bias = *(const f32x4*)(bv + MI.v*16 + 4*g);
            sfor<0, 4>([&](auto NI) { acc[MI.v][NI.v] = bias; });
        });
        sfor<0, 2>([&](auto KC) {
            s16x8 bh[4], bl[4];
            sfor<0, 4>([&](auto NI) {
                int px  = NI.v*16 + lm;
                int blk = (4*KC.v + g) ^ (px & 7);
                const char* p0 = (const char*)hbuf + px*128 + blk*16;
                bh[NI.v] = *(const s16x8*)(p0);
                bl[NI.v] = *(const s16x8*)(p0 + 8192);
            });
            sfor<0, 4>([&](auto MI) {
                int off = (MI.v*16 + lm)*64 + KC.v*32 + g*8;
                s16x8 ah = *(const s16x8*)(whl + off);
                s16x8 al = *(const s16x8*)(wll + off);
                sfor<0, 4>([&](auto NI) {
                    f32x4 a = acc[MI.v][NI.v];
                    a = __builtin_amdgcn_mfma_f32_16x16x32_bf16(ah, bh[NI.v], a, 0, 0, 0);
                    a = __builtin_amdgcn_mfma_f32_16x16x32_bf16(ah, bl[NI.v], a, 0, 0, 0);
                    a = __builtin_amdgcn_mfma_f32_16x16x32_bf16(al, bh[NI.v], a, 0, 0, 0);
                    acc[MI.v][NI.v] = a;
                });
            });
        });
        __syncthreads();
        const float* pcl = pcq + l*768;
        sfor<0, 4>([&](auto MI) {
            f32x4 vo[4];
            sfor<0, 4>([&](auto R) {
                const float* q = pcl + (MI.v*16 + 4*g + R.v)*12;
                f32x4 qa = *(const f32x4*)q, qb = *(const f32x4*)(q + 4);
                float br = q[8];
                sfor<0, 4>([&](auto NI) {
                    vo[NI.v][R.v] = geval(qa, qb, br, x0v[NI.v], x1v[NI.v],
                                          x02v[NI.v], x11v[NI.v], x12v[NI.v])
                                    * acc[MI.v][NI.v][R.v];
                });
            });
            sfor<0, 4>([&](auto NI) {
                s16x4 fh, fl;
                sfor<0, 4>([&](auto R) {
                    float v = vo[NI.v][R.v];
                    ushort_t h = bf16_hi(v);
                    fh[R.v] = (short)h;
                    fl[R.v] = (short)bf16_hi(v - bf16_tof(h));
                });
                int px  = NI.v*16 + lm;
                int blk = (2*MI.v + (g >> 1)) ^ (px & 7);
                char* p0 = (char*)hbuf + px*128 + blk*16 + (g & 1)*8;
                *(s16x4*)(p0)        = fh;
                *(s16x4*)(p0 + 8192) = fl;
            });
        });
    }

    // ---- output: out[o,px] = Wout[o,k] h4[k,px] + out_b ----
    __syncthreads();
    f32x4 ao[4];
    sfor<0, 4>([&](auto NI) { ao[NI.v] = (f32x4)(0.0f); });
    sfor<0, 2>([&](auto KC) {
        s16x8 bh[4], bl[4];
        sfor<0, 4>([&](auto NI) {
            int px  = NI.v*16 + lm;
            int blk = (4*KC.v + g) ^ (px & 7);
            const char* p0 = (const char*)hbuf + px*128 + blk*16;
            bh[NI.v] = *(const s16x8*)(p0);
            bl[NI.v] = *(const s16x8*)(p0 + 8192);
        });
        int off = lm*64 + KC.v*32 + g*8;
        s16x8 ah = *(const s16x8*)(wouthi + off);
        s16x8 al = *(const s16x8*)(woutlo + off);
        sfor<0, 4>([&](auto NI) {
            f32x4 a = ao[NI.v];
            a = __builtin_amdgcn_mfma_f32_16x16x32_bf16(ah, bh[NI.v], a, 0, 0, 0);
            a = __builtin_amdgcn_mfma_f32_16x16x32_bf16(ah, bl[NI.v], a, 0, 0, 0);
            a = __builtin_amdgcn_mfma_f32_16x16x32_bf16(al, bh[NI.v], a, 0, 0, 0);
            ao[NI.v] = a;
        });
    });
    if (lane < 16) {   // rows 0..3 live on g==0; out channels = rows 0..2
        float ob0 = out_b[0], ob1 = out_b[1], ob2 = out_b[2];
        sfor<0, 4>([&](auto NI) {
            float* po = out + pixo[NI.v];
            po[0]     = ao[NI.v][0] + ob0;
            po[HW2]   = ao[NI.v][1] + ob1;
            po[2*HW2] = ao[NI.v][2] + ob2;
        });
    }
}

extern "C" void kernel_launch(void* const* d_in, const int* in_sizes, int n_in,
                              void* d_out, int out_size, void* d_ws, size_t ws_size,
                              hipStream_t stream) {
    const float* x      = (const float*)d_in[0];
    const float* filt_w = (const float*)d_in[1];
    const float* filt_b = (const float*)d_in[2];
    const float* mu     = (const float*)d_in[3];
    const float* gamma  = (const float*)d_in[4];
    const float* theta  = (const float*)d_in[5];
    const float* lin_w  = (const float*)d_in[6];
    const float* lin_b  = (const float*)d_in[7];
    const float* out_w  = (const float*)d_in[8];
    const float* out_b  = (const float*)d_in[9];

    char* ws = (char*)d_ws;
    float*    pcq    = (float*)ws;
    ushort_t* whi    = (ushort_t*)(ws + WS_WHI);
    ushort_t* wlo    = (ushort_t*)(ws + WS_WLO);
    ushort_t* wouthi = (ushort_t*)(ws + WS_WOH);
    ushort_t* woutlo = (ushort_t*)(ws + WS_WOL);

    gabor_pre<<<70, 256, 0, stream>>>(filt_w, filt_b, mu, gamma, theta,
                                      lin_w, out_w, pcq, whi, wlo, wouthi, woutlo);
    gabor_mfma<<<4096, 128, 0, stream>>>(x, lin_b, out_b, pcq, whi, wlo,
                                         wouthi, woutlo, (float*)d_out);
}